// Round 5
// baseline (314.743 us; speedup 1.0000x reference)
//
#include <hip/hip_runtime.h>
#include <hip/hip_bf16.h>
#include <hip/hip_fp8.h>

typedef __bf16 bf16x8 __attribute__((ext_vector_type(8)));
typedef float floatx4 __attribute__((ext_vector_type(4)));
typedef float floatx16 __attribute__((ext_vector_type(16)));

// ---- Cl(3) Cayley table, row i = first operand, col j = second. p = i*8+j ----
constexpr int TK[64] = {
  0,1,2,3,4,5,6,7,
  1,0,4,5,2,3,7,6,
  2,4,0,6,1,7,3,5,
  3,5,6,0,7,1,2,4,
  4,2,1,7,0,6,5,3,
  5,3,7,1,6,0,4,2,
  6,7,3,2,5,4,0,1,
  7,6,5,4,3,2,1,0
};
constexpr float SGN[64] = {
  1, 1, 1, 1, 1, 1, 1, 1,
  1, 1, 1, 1, 1, 1, 1, 1,
  1,-1, 1, 1,-1,-1, 1,-1,
  1,-1,-1, 1, 1,-1,-1, 1,
  1,-1, 1, 1,-1,-1, 1,-1,
  1,-1,-1, 1, 1,-1,-1, 1,
  1, 1,-1, 1,-1, 1,-1,-1,
  1, 1,-1, 1,-1, 1,-1,-1
};

__device__ __forceinline__ void async16(const void* g, void* l) {
  __builtin_amdgcn_global_load_lds(
      (const __attribute__((address_space(1))) void*)g,
      (__attribute__((address_space(3))) void*)l, 16, 0, 0);
}

__device__ __forceinline__ unsigned char to_fp8(float v) {
  __hip_fp8_e4m3 q(v);
  return (unsigned char)q.__x;
}

// ---- merged weight transposes: z=0 Wg->Bg bf16, z=1 Wu->Bu bf16, z=2 Wd->Bd fp8 ----
__global__ __launch_bounds__(256) void transpose_all(
    const float* __restrict__ Wg, const float* __restrict__ Wu,
    const float* __restrict__ Wd,
    __bf16* __restrict__ Bg, __bf16* __restrict__ Bu,
    unsigned char* __restrict__ Bd)
{
  __shared__ float s[32 * 33];
  const int z = blockIdx.y;
  const int b = blockIdx.x;
  const int t = threadIdx.x;
  const int r = t >> 5, c = t & 31;
  if (z < 2) {
    const float* src = z ? Wu : Wg;
    __bf16* dst = z ? Bu : Bg;
    const int n0 = (b & 31) * 32, k0 = (b >> 5) * 32;   // K=256, N=1024
    #pragma unroll
    for (int i = 0; i < 4; ++i)
      s[(r + i * 8) * 33 + c] = src[(size_t)(k0 + r + i * 8) * 1024 + n0 + c];
    __syncthreads();
    #pragma unroll
    for (int i = 0; i < 4; ++i)
      dst[(size_t)(n0 + r + i * 8) * 256 + k0 + c] = (__bf16)s[c * 33 + r + i * 8];
  } else {
    const int n0 = (b & 7) * 32, k0 = (b >> 3) * 32;    // K=1024, N=256
    #pragma unroll
    for (int i = 0; i < 4; ++i)
      s[(r + i * 8) * 33 + c] = Wd[(size_t)(k0 + r + i * 8) * 256 + n0 + c];
    __syncthreads();
    #pragma unroll
    for (int i = 0; i < 4; ++i)
      Bd[(size_t)(n0 + r + i * 8) * 1024 + k0 + c] = to_fp8(16.f * s[c * 33 + r + i * 8]);
  }
}

// ---- geometric product + gate mix + LayerNorm -> bf16 flat [65536][256] ----
__global__ __launch_bounds__(256) void geo_ln(
    const float* __restrict__ X,   // [8192][8][256]
    const float* __restrict__ IW,  // [64]
    const float* __restrict__ GG,  // [1]
    const float* __restrict__ LW, const float* __restrict__ LB,
    __bf16* __restrict__ F)        // [65536][256]
{
  __shared__ float sw[64];
  __shared__ float smix[8 * 256];
  __shared__ float sstat[16];
  const int t = threadIdx.x;
  const int tok = blockIdx.x;

  if (t < 64) sw[t] = SGN[t] / (1.f + __expf(-IW[t]));

  float xv[8];
  #pragma unroll
  for (int b = 0; b < 8; ++b) xv[b] = X[(size_t)tok * 2048 + b * 256 + t];
  const float g = 1.f / (1.f + __expf(-GG[0]));

  __syncthreads();

  float geo[8] = {0.f, 0.f, 0.f, 0.f, 0.f, 0.f, 0.f, 0.f};
  #pragma unroll
  for (int p = 0; p < 64; ++p)
    geo[TK[p]] += xv[p >> 3] * xv[p & 7] * sw[p];

  float mv[8];
  #pragma unroll
  for (int b = 0; b < 8; ++b) {
    mv[b] = g * geo[b] + (1.f - g) * xv[b];
    smix[b * 256 + t] = mv[b];
  }
  __syncthreads();

  const int wv = t >> 6, lane = t & 63;
  #pragma unroll
  for (int s = 0; s < 2; ++s) {
    int b = wv * 2 + s;
    float v0 = smix[b * 256 + lane];
    float v1 = smix[b * 256 + 64 + lane];
    float v2 = smix[b * 256 + 128 + lane];
    float v3 = smix[b * 256 + 192 + lane];
    float sum = v0 + v1 + v2 + v3;
    float sq  = v0*v0 + v1*v1 + v2*v2 + v3*v3;
    #pragma unroll
    for (int off = 32; off > 0; off >>= 1) {
      sum += __shfl_xor(sum, off, 64);
      sq  += __shfl_xor(sq,  off, 64);
    }
    if (lane == 0) {
      float mu  = sum * (1.f / 256.f);
      float var = sq * (1.f / 256.f) - mu * mu;
      sstat[b]     = mu;
      sstat[8 + b] = rsqrtf(var + 1e-5f);
    }
  }
  __syncthreads();

  const float lw = LW[t], lb = LB[t];
  #pragma unroll
  for (int b = 0; b < 8; ++b) {
    float v = (mv[b] - sstat[b]) * sstat[8 + b] * lw + lb;
    F[(size_t)(tok * 8 + b) * 256 + t] = (__bf16)v;
  }
}

// ---- Kernel C: gate+up GEMM + SwiGLU -> h fp8 (x16) ----
// tile 128m x 64f, BK=64, 4 waves. B (gate/up weights) loaded DIRECT global->VGPR
// (L1/L2-resident 32KB f-slice, shared by 16 blocks via XCD swizzle) -- no B LDS.
// A double-buffered in 2x16KB LDS; ONE __syncthreads per K-tile (its implicit
// vmcnt(0) drains only the A-stage issued a full tile earlier). Operand-swapped
// 32x32x16 MFMA (acc=C^T), hw packed fp8 epilogue, pad-17 repack.
__global__ __launch_bounds__(256, 4) void gemm_gateup(
    const __bf16* __restrict__ A,   // flat [65536][256]
    const __bf16* __restrict__ Bg,  // [1024][256]
    const __bf16* __restrict__ Bu,  // [1024][256]
    unsigned char* __restrict__ H)  // fp8 [65536][1024]
{
  __shared__ __align__(16) char smem[32768];    // A dbuf: 2 x [128][64] bf16
  __bf16* sA = (__bf16*)smem;
  int* sD = (int*)smem;                         // epilogue alias (buf0 region)

  const int t = threadIdx.x;
  const int bid = blockIdx.y * 16 + blockIdx.x;
  const int lid = (bid & 7) * 1024 + (bid >> 3);   // bijective XCD swizzle
  const int f0 = (lid & 15) * 64;
  const int m0 = (lid >> 4) * 128;
  const int lane = t & 63, wv = t >> 6;
  const int wm = wv & 1, wf = wv >> 1;
  const int l31 = lane & 31, half = lane >> 5;

  int aoff[4];
  #pragma unroll
  for (int i = 0; i < 4; ++i) {
    int idx = i * 256 + t, row = idx >> 3, slot = idx & 7;
    aoff[i] = (m0 + row) * 256 + (slot ^ (row & 7) ^ ((row >> 3) & 3)) * 8;
  }

  // per-lane direct B addresses: row = f0+wf*32+l31, k-chunk = kk + s*16 + half*8
  const __bf16* gBg = Bg + (size_t)(f0 + wf * 32 + l31) * 256 + half * 8;
  const __bf16* gBu = Bu + (size_t)(f0 + wf * 32 + l31) * 256 + half * 8;

  floatx16 accg[2], accu[2];
  #pragma unroll
  for (int i = 0; i < 2; ++i)
    #pragma unroll
    for (int r = 0; r < 16; ++r) { accg[i][r] = 0.f; accu[i][r] = 0.f; }

  const int xr = (l31 & 7) ^ ((l31 >> 3) & 3);
  const int rowA0 = (wm * 64 + l31) * 64;
  const int rowA1 = rowA0 + 32 * 64;

  // prologue: stage tile 0 into buf0
  #pragma unroll
  for (int i = 0; i < 4; ++i) async16(A + aoff[i], &sA[(i * 256 + t) * 8]);

  #pragma unroll
  for (int k = 0; k < 4; ++k) {
    const int kk = k * 64;
    // drains only the A-stage issued one tile ago (implicit vmcnt(0)+lgkmcnt(0))
    __syncthreads();

    // B direct loads for this tile (issued FIRST, before next stage)
    bf16x8 bgv[4], buv[4];
    #pragma unroll
    for (int s = 0; s < 4; ++s) {
      bgv[s] = *(const bf16x8*)(gBg + kk + s * 16);
      buv[s] = *(const bf16x8*)(gBu + kk + s * 16);
    }
    __builtin_amdgcn_sched_barrier(0);   // pin: B loads before A-stage in issue order

    if (k < 3) {
      const int nb = ((k + 1) & 1) * 8192;   // element offset of other buf
      #pragma unroll
      for (int i = 0; i < 4; ++i)
        async16(A + aoff[i] + kk + 64, &sA[nb + (i * 256 + t) * 8]);
    }

    const __bf16* cur = sA + (k & 1) * 8192;
    #pragma unroll
    for (int s = 0; s < 4; ++s) {   // k16 steps
      const int oct = ((s * 2 + half) ^ xr) * 8;
      bf16x8 a0 = *(const bf16x8*)&cur[rowA0 + oct];
      bf16x8 a1 = *(const bf16x8*)&cur[rowA1 + oct];
      // operand-swapped: acc = C^T, lane col = m, reg row = f
      accg[0] = __builtin_amdgcn_mfma_f32_32x32x16_bf16(bgv[s], a0, accg[0], 0, 0, 0);
      accu[0] = __builtin_amdgcn_mfma_f32_32x32x16_bf16(buv[s], a0, accu[0], 0, 0, 0);
      accg[1] = __builtin_amdgcn_mfma_f32_32x32x16_bf16(bgv[s], a1, accg[1], 0, 0, 0);
      accu[1] = __builtin_amdgcn_mfma_f32_32x32x16_bf16(buv[s], a1, accu[1], 0, 0, 0);
    }
  }

  // ---- epilogue: silu(g)*u -> packed fp8 dwords, pad-17 LDS tile [128][17] ----
  // last K-tile read buf1; sD aliases buf0 (last read at k=2, all waves past
  // k=3's barrier) -> safe to write immediately.
  #pragma unroll
  for (int i = 0; i < 2; ++i) {
    const int m_l = wm * 64 + i * 32 + l31;
    #pragma unroll
    for (int q = 0; q < 4; ++q) {
      float hv[4];
      #pragma unroll
      for (int e = 0; e < 4; ++e) {
        float gv = accg[i][q * 4 + e], uv = accu[i][q * 4 + e];
        hv[e] = 16.f * (gv / (1.f + __expf(-gv))) * uv;
      }
      int w = __builtin_amdgcn_cvt_pk_fp8_f32(hv[0], hv[1], 0, false);
      w = __builtin_amdgcn_cvt_pk_fp8_f32(hv[2], hv[3], w, true);
      sD[m_l * 17 + wf * 8 + half + 2 * q] = w;   // bank 17m+fd: 2-way, free
    }
  }
  __syncthreads();
  #pragma unroll
  for (int c = 0; c < 2; ++c) {
    int chunk = c * 256 + t;        // 512 chunks of 16 B
    int m = chunk >> 2, q4 = chunk & 3;
    int4 v;
    v.x = sD[m * 17 + q4 * 4 + 0];
    v.y = sD[m * 17 + q4 * 4 + 1];
    v.z = sD[m * 17 + q4 * 4 + 2];
    v.w = sD[m * 17 + q4 * 4 + 3];
    *(int4*)&H[(size_t)(m0 + m) * 1024 + f0 + q4 * 16] = v;
  }
}

// ---- Kernel D: fp8 down GEMM + residual. tile 128m x 256n, BK=64 ----
__global__ __launch_bounds__(256, 2) void gemm_down(
    const unsigned char* __restrict__ A,   // h fp8 [65536][1024]
    const unsigned char* __restrict__ B,   // Wd^T fp8 [256][1024]
    const float* __restrict__ X,
    float* __restrict__ O)
{
  __shared__ unsigned char sA[128 * 64];   // 8 KB
  __shared__ unsigned char sB[256 * 64];   // 16 KB
  const int t = threadIdx.x;
  const int m0 = blockIdx.x * 128;
  const int lane = t & 63, wv = t >> 6;
  const int wm = wv & 1, wn = wv >> 1;
  const int l15 = lane & 15, quad = lane >> 4;

  int aoff[2], boff[4];
  #pragma unroll
  for (int i = 0; i < 2; ++i) {
    int idx = i * 256 + t, row = idx >> 2, q = idx & 3;
    aoff[i] = (m0 + row) * 1024 + (q ^ ((row >> 1) & 3)) * 16;
  }
  #pragma unroll
  for (int i = 0; i < 4; ++i) {
    int idx = i * 256 + t, row = idx >> 2, q = idx & 3;
    boff[i] = row * 1024 + (q ^ ((row >> 1) & 3)) * 16;
  }

  floatx4 zero = {0.f, 0.f, 0.f, 0.f};
  floatx4 acc[4][8];
  #pragma unroll
  for (int i = 0; i < 4; ++i)
    #pragma unroll
    for (int j = 0; j < 8; ++j) acc[i][j] = zero;

  int aaddr[2][4], baddr[2][8];
  #pragma unroll
  for (int s = 0; s < 2; ++s) {
    const int u = s * 4 + quad;
    #pragma unroll
    for (int i = 0; i < 4; ++i) {
      int r = wm * 64 + i * 16 + l15;
      aaddr[s][i] = r * 64 + (((u >> 1) ^ ((r >> 1) & 3)) << 4) + (u & 1) * 8;
    }
    #pragma unroll
    for (int j = 0; j < 8; ++j) {
      int r = wn * 128 + j * 16 + l15;
      baddr[s][j] = r * 64 + (((u >> 1) ^ ((r >> 1) & 3)) << 4) + (u & 1) * 8;
    }
  }

  for (int k = 0; k < 16; ++k) {    // k0 = k*64 (bytes == elements)
    const int kk = k * 64;
    #pragma unroll
    for (int i = 0; i < 2; ++i) async16(A + aoff[i] + kk, &sA[(i * 256 + t) * 16]);
    #pragma unroll
    for (int i = 0; i < 4; ++i) async16(B + boff[i] + kk, &sB[(i * 256 + t) * 16]);
    __syncthreads();

    #pragma unroll
    for (int s = 0; s < 2; ++s) {
      long av[4], bv[8];
      #pragma unroll
      for (int i = 0; i < 4; ++i) av[i] = *(const long*)&sA[aaddr[s][i]];
      #pragma unroll
      for (int j = 0; j < 8; ++j) bv[j] = *(const long*)&sB[baddr[s][j]];
      #pragma unroll
      for (int i = 0; i < 4; ++i)
        #pragma unroll
        for (int j = 0; j < 8; ++j)
          acc[i][j] = __builtin_amdgcn_mfma_f32_16x16x32_fp8_fp8(av[i], bv[j], acc[i][j], 0, 0, 0);
    }
    __syncthreads();
  }

  #pragma unroll
  for (int i = 0; i < 4; ++i)
    #pragma unroll
    for (int j = 0; j < 8; ++j)
      #pragma unroll
      for (int r = 0; r < 4; ++r) {
        int m = m0 + wm * 64 + i * 16 + quad * 4 + r;
        int n = wn * 128 + j * 16 + l15;
        size_t o = (size_t)m * 256 + n;
        O[o] = X[o] + acc[i][j][r] * (1.f / 256.f);
      }
}

extern "C" void kernel_launch(void* const* d_in, const int* in_sizes, int n_in,
                              void* d_out, int out_size, void* d_ws, size_t ws_size,
                              hipStream_t stream) {
  const float* x   = (const float*)d_in[0];
  const float* iw  = (const float*)d_in[1];
  const float* gg  = (const float*)d_in[2];
  const float* lnw = (const float*)d_in[3];
  const float* lnb = (const float*)d_in[4];
  const float* Wg  = (const float*)d_in[5];
  const float* Wu  = (const float*)d_in[6];
  const float* Wd  = (const float*)d_in[7];
  float* out = (float*)d_out;

  char* ws = (char*)d_ws;
  __bf16*        flat = (__bf16*)(ws);                       // 32 MB
  unsigned char* h    = (unsigned char*)(ws + 33554432);     // 64 MB
  __bf16*        Bg   = (__bf16*)(ws + 100663296);           // 512 KB
  __bf16*        Bu   = (__bf16*)(ws + 101187584);           // 512 KB
  unsigned char* Bd   = (unsigned char*)(ws + 101711872);    // 256 KB

  transpose_all<<<dim3(256, 3), 256, 0, stream>>>(Wg, Wu, Wd, Bg, Bu, Bd);
  geo_ln<<<8192, 256, 0, stream>>>(x, iw, gg, lnw, lnb, flat);
  gemm_gateup<<<dim3(16, 512), 256, 0, stream>>>(flat, Bg, Bu, h);
  gemm_down<<<512, 256, 0, stream>>>(h, Bd, x, out);
}

// Round 7
// 275.696 us; speedup vs baseline: 1.1416x; 1.1416x over previous
//
#include <hip/hip_runtime.h>
#include <hip/hip_bf16.h>
#include <hip/hip_fp8.h>

typedef __bf16 bf16x8 __attribute__((ext_vector_type(8)));
typedef float floatx4 __attribute__((ext_vector_type(4)));
typedef float floatx16 __attribute__((ext_vector_type(16)));

// ---- Cl(3) Cayley table, row i = first operand, col j = second. p = i*8+j ----
constexpr int TK[64] = {
  0,1,2,3,4,5,6,7,
  1,0,4,5,2,3,7,6,
  2,4,0,6,1,7,3,5,
  3,5,6,0,7,1,2,4,
  4,2,1,7,0,6,5,3,
  5,3,7,1,6,0,4,2,
  6,7,3,2,5,4,0,1,
  7,6,5,4,3,2,1,0
};
constexpr float SGN[64] = {
  1, 1, 1, 1, 1, 1, 1, 1,
  1, 1, 1, 1, 1, 1, 1, 1,
  1,-1, 1, 1,-1,-1, 1,-1,
  1,-1,-1, 1, 1,-1,-1, 1,
  1,-1, 1, 1,-1,-1, 1,-1,
  1,-1,-1, 1, 1,-1,-1, 1,
  1, 1,-1, 1,-1, 1,-1,-1,
  1, 1,-1, 1,-1, 1,-1,-1
};

__device__ __forceinline__ void async16(const void* g, void* l) {
  __builtin_amdgcn_global_load_lds(
      (const __attribute__((address_space(1))) void*)g,
      (__attribute__((address_space(3))) void*)l, 16, 0, 0);
}

__device__ __forceinline__ unsigned char to_fp8(float v) {
  __hip_fp8_e4m3 q(v);
  return (unsigned char)q.__x;
}

// ---- merged weight transposes: z=0 Wg->Bg bf16, z=1 Wu->Bu bf16, z=2 Wd->Bd fp8 ----
__global__ __launch_bounds__(256) void transpose_all(
    const float* __restrict__ Wg, const float* __restrict__ Wu,
    const float* __restrict__ Wd,
    __bf16* __restrict__ Bg, __bf16* __restrict__ Bu,
    unsigned char* __restrict__ Bd)
{
  __shared__ float s[32 * 33];
  const int z = blockIdx.y;
  const int b = blockIdx.x;
  const int t = threadIdx.x;
  const int r = t >> 5, c = t & 31;
  if (z < 2) {
    const float* src = z ? Wu : Wg;
    __bf16* dst = z ? Bu : Bg;
    const int n0 = (b & 31) * 32, k0 = (b >> 5) * 32;   // K=256, N=1024
    #pragma unroll
    for (int i = 0; i < 4; ++i)
      s[(r + i * 8) * 33 + c] = src[(size_t)(k0 + r + i * 8) * 1024 + n0 + c];
    __syncthreads();
    #pragma unroll
    for (int i = 0; i < 4; ++i)
      dst[(size_t)(n0 + r + i * 8) * 256 + k0 + c] = (__bf16)s[c * 33 + r + i * 8];
  } else {
    const int n0 = (b & 7) * 32, k0 = (b >> 3) * 32;    // K=1024, N=256
    #pragma unroll
    for (int i = 0; i < 4; ++i)
      s[(r + i * 8) * 33 + c] = Wd[(size_t)(k0 + r + i * 8) * 256 + n0 + c];
    __syncthreads();
    #pragma unroll
    for (int i = 0; i < 4; ++i)
      Bd[(size_t)(n0 + r + i * 8) * 1024 + k0 + c] = to_fp8(16.f * s[c * 33 + r + i * 8]);
  }
}

// ---- geometric product + gate mix + LayerNorm -> bf16 flat [65536][256] ----
// v2: one wave per token; float4 loads; all-register products; wave-shfl LN.
__global__ __launch_bounds__(256) void geo_ln(
    const float* __restrict__ X,   // [8192][8][256]
    const float* __restrict__ IW,  // [64]
    const float* __restrict__ GG,  // [1]
    const float* __restrict__ LW, const float* __restrict__ LB,
    __bf16* __restrict__ F)        // [65536][256]
{
  __shared__ float sw[64];
  const int t = threadIdx.x;
  const int wv = t >> 6, lane = t & 63;
  const int tok = blockIdx.x * 4 + wv;

  if (t < 64) sw[t] = SGN[t] / (1.f + __expf(-IW[t]));
  const float g = 1.f / (1.f + __expf(-GG[0]));

  floatx4 xv[8];
  #pragma unroll
  for (int b = 0; b < 8; ++b)
    xv[b] = *(const floatx4*)&X[(size_t)tok * 2048 + b * 256 + lane * 4];
  const floatx4 lw4 = *(const floatx4*)&LW[lane * 4];
  const floatx4 lb4 = *(const floatx4*)&LB[lane * 4];

  __syncthreads();

  floatx4 geo[8];
  #pragma unroll
  for (int b = 0; b < 8; ++b) geo[b] = floatx4{0.f, 0.f, 0.f, 0.f};
  #pragma unroll
  for (int p = 0; p < 64; ++p)
    geo[TK[p]] += xv[p >> 3] * xv[p & 7] * sw[p];

  #pragma unroll
  for (int b = 0; b < 8; ++b) {
    floatx4 m4 = g * geo[b] + (1.f - g) * xv[b];
    float s = m4[0] + m4[1] + m4[2] + m4[3];
    float q = m4[0]*m4[0] + m4[1]*m4[1] + m4[2]*m4[2] + m4[3]*m4[3];
    #pragma unroll
    for (int off = 32; off > 0; off >>= 1) {
      s += __shfl_xor(s, off, 64);
      q += __shfl_xor(q, off, 64);
    }
    float mu = s * (1.f / 256.f);
    float rstd = rsqrtf(q * (1.f / 256.f) - mu * mu + 1e-5f);
    floatx4 v = (m4 - mu) * rstd * lw4 + lb4;
    union { __bf16 h[4]; short4 s4; } u;
    u.h[0] = (__bf16)v[0]; u.h[1] = (__bf16)v[1];
    u.h[2] = (__bf16)v[2]; u.h[3] = (__bf16)v[3];
    *(short4*)&F[(size_t)(tok * 8 + b) * 256 + lane * 4] = u.s4;
  }
}

// ---- Kernel C: gate+up GEMM + SwiGLU -> h fp8 (x16) ----
// r4 verified config (106 us): tile 128m x 64f, BK=64, 4 waves, 3 blocks/CU.
// Operand-swapped 32x32x16 MFMA, hw packed fp8 epilogue, full swizzle, XCD swizzle.
__global__ __launch_bounds__(256, 3) void gemm_gateup(
    const __bf16* __restrict__ A,   // flat [65536][256]
    const __bf16* __restrict__ Bg,  // [1024][256]
    const __bf16* __restrict__ Bu,  // [1024][256]
    unsigned char* __restrict__ H)  // fp8 [65536][1024]
{
  __shared__ __align__(16) char smem[32768];
  __bf16* sA  = (__bf16*)smem;                  // 16 KB [128][64]
  __bf16* sBg = (__bf16*)(smem + 16384);        // 8 KB  [64][64]
  __bf16* sBu = (__bf16*)(smem + 24576);        // 8 KB  [64][64]
  int* sD = (int*)(smem + 16384);               // 8.5 KB alias (post-loop) [128][17]

  const int t = threadIdx.x;
  const int bid = blockIdx.y * 16 + blockIdx.x;
  const int lid = (bid & 7) * 1024 + (bid >> 3);   // bijective XCD swizzle
  const int f0 = (lid & 15) * 64;
  const int m0 = (lid >> 4) * 128;
  const int lane = t & 63, wv = t >> 6;
  const int wm = wv & 1, wf = wv >> 1;
  const int l31 = lane & 31, half = lane >> 5;

  int aoff[4], boff[2];
  #pragma unroll
  for (int i = 0; i < 4; ++i) {
    int idx = i * 256 + t, row = idx >> 3, slot = idx & 7;
    aoff[i] = (m0 + row) * 256 + (slot ^ (row & 7) ^ ((row >> 3) & 3)) * 8;
  }
  #pragma unroll
  for (int i = 0; i < 2; ++i) {
    int idx = i * 256 + t, row = idx >> 3, slot = idx & 7;
    boff[i] = (f0 + row) * 256 + (slot ^ (row & 7) ^ ((row >> 3) & 3)) * 8;
  }

  floatx16 accg[2], accu[2];
  #pragma unroll
  for (int i = 0; i < 2; ++i)
    #pragma unroll
    for (int r = 0; r < 16; ++r) { accg[i][r] = 0.f; accu[i][r] = 0.f; }

  const int xr = (l31 & 7) ^ ((l31 >> 3) & 3);
  const int rowA0 = (wm * 64 + l31) * 64;       // element offset of A row
  const int rowA1 = rowA0 + 32 * 64;
  const int rowB  = (wf * 32 + l31) * 64;

  for (int k = 0; k < 4; ++k) {     // k0 = k*64
    const int kk = k * 64;
    #pragma unroll
    for (int i = 0; i < 4; ++i) async16(A + aoff[i] + kk, &sA[(i * 256 + t) * 8]);
    #pragma unroll
    for (int i = 0; i < 2; ++i) {
      async16(Bg + boff[i] + kk, &sBg[(i * 256 + t) * 8]);
      async16(Bu + boff[i] + kk, &sBu[(i * 256 + t) * 8]);
    }
    __syncthreads();

    #pragma unroll
    for (int s = 0; s < 4; ++s) {   // k16 steps
      const int oct = ((s * 2 + half) ^ xr) * 8;
      bf16x8 a0 = *(const bf16x8*)&sA[rowA0 + oct];
      bf16x8 a1 = *(const bf16x8*)&sA[rowA1 + oct];
      bf16x8 bg = *(const bf16x8*)&sBg[rowB + oct];
      bf16x8 bu = *(const bf16x8*)&sBu[rowB + oct];
      // operand-swapped: acc = C^T, lane col = m, reg row = f
      accg[0] = __builtin_amdgcn_mfma_f32_32x32x16_bf16(bg, a0, accg[0], 0, 0, 0);
      accu[0] = __builtin_amdgcn_mfma_f32_32x32x16_bf16(bu, a0, accu[0], 0, 0, 0);
      accg[1] = __builtin_amdgcn_mfma_f32_32x32x16_bf16(bg, a1, accg[1], 0, 0, 0);
      accu[1] = __builtin_amdgcn_mfma_f32_32x32x16_bf16(bu, a1, accu[1], 0, 0, 0);
    }
    __syncthreads();
  }

  // ---- epilogue: silu(g)*u -> packed fp8 dwords, pad-17 LDS tile [128][17] ----
  #pragma unroll
  for (int i = 0; i < 2; ++i) {
    const int m_l = wm * 64 + i * 32 + l31;
    #pragma unroll
    for (int q = 0; q < 4; ++q) {
      float hv[4];
      #pragma unroll
      for (int e = 0; e < 4; ++e) {
        float gv = accg[i][q * 4 + e], uv = accu[i][q * 4 + e];
        hv[e] = 16.f * (gv / (1.f + __expf(-gv))) * uv;
      }
      int w = __builtin_amdgcn_cvt_pk_fp8_f32(hv[0], hv[1], 0, false);
      w = __builtin_amdgcn_cvt_pk_fp8_f32(hv[2], hv[3], w, true);
      sD[m_l * 17 + wf * 8 + half + 2 * q] = w;   // bank 17m+fd: 2-way, free
    }
  }
  __syncthreads();
  #pragma unroll
  for (int c = 0; c < 2; ++c) {
    int chunk = c * 256 + t;        // 512 chunks of 16 B
    int m = chunk >> 2, q4 = chunk & 3;
    int4 v;
    v.x = sD[m * 17 + q4 * 4 + 0];
    v.y = sD[m * 17 + q4 * 4 + 1];
    v.z = sD[m * 17 + q4 * 4 + 2];
    v.w = sD[m * 17 + q4 * 4 + 3];
    *(int4*)&H[(size_t)(m0 + m) * 1024 + f0 + q4 * 16] = v;
  }
}

// ---- Kernel D v2: fp8 down GEMM + residual. tile 128m x 128n, BK=64 ----
// 1024 blocks = 4 blocks/CU; LDS double-buffered (h + Wd), ONE barrier per
// K-tile (drains the stage issued one iteration earlier -- free wait).
__global__ __launch_bounds__(256, 4) void gemm_down(
    const unsigned char* __restrict__ A,   // h fp8 [65536][1024]
    const unsigned char* __restrict__ B,   // Wd^T fp8 [256][1024]
    const float* __restrict__ X,
    float* __restrict__ O)
{
  __shared__ unsigned char sH[2][8192];   // [128][64] fp8 x2
  __shared__ unsigned char sW[2][8192];   // [128][64] fp8 x2
  const int t = threadIdx.x;
  const int m0 = blockIdx.y * 128;
  const int n0 = blockIdx.x * 128;
  const int lane = t & 63, wv = t >> 6;
  const int wm = wv & 1, wn = wv >> 1;
  const int l15 = lane & 15, quad = lane >> 4;

  int aoff[2], boff[2];
  #pragma unroll
  for (int i = 0; i < 2; ++i) {
    int idx = i * 256 + t, row = idx >> 2, q = idx & 3;
    aoff[i] = (m0 + row) * 1024 + (q ^ ((row >> 1) & 3)) * 16;
    boff[i] = (n0 + row) * 1024 + (q ^ ((row >> 1) & 3)) * 16;
  }

  floatx4 zero = {0.f, 0.f, 0.f, 0.f};
  floatx4 acc[4][4];
  #pragma unroll
  for (int i = 0; i < 4; ++i)
    #pragma unroll
    for (int j = 0; j < 4; ++j) acc[i][j] = zero;

  int aaddr[2][4], baddr[2][4];
  #pragma unroll
  for (int s = 0; s < 2; ++s) {
    const int u = s * 4 + quad;
    #pragma unroll
    for (int i = 0; i < 4; ++i) {
      int r = wm * 64 + i * 16 + l15;
      aaddr[s][i] = r * 64 + (((u >> 1) ^ ((r >> 1) & 3)) << 4) + (u & 1) * 8;
    }
    #pragma unroll
    for (int j = 0; j < 4; ++j) {
      int r = wn * 64 + j * 16 + l15;
      baddr[s][j] = r * 64 + (((u >> 1) ^ ((r >> 1) & 3)) << 4) + (u & 1) * 8;
    }
  }

  // prologue: stage tile 0 into buf 0
  #pragma unroll
  for (int i = 0; i < 2; ++i) {
    async16(A + aoff[i], &sH[0][(i * 256 + t) * 16]);
    async16(B + boff[i], &sW[0][(i * 256 + t) * 16]);
  }

  for (int k = 0; k < 16; ++k) {
    const int cur = k & 1;
    // drains stage issued one iteration ago (implicit vmcnt(0)+lgkmcnt(0))
    __syncthreads();
    if (k < 15) {
      const int kk = (k + 1) * 64, nb = cur ^ 1;
      #pragma unroll
      for (int i = 0; i < 2; ++i) {
        async16(A + aoff[i] + kk, &sH[nb][(i * 256 + t) * 16]);
        async16(B + boff[i] + kk, &sW[nb][(i * 256 + t) * 16]);
      }
    }

    #pragma unroll
    for (int s = 0; s < 2; ++s) {
      long av[4], bv[4];
      #pragma unroll
      for (int i = 0; i < 4; ++i) av[i] = *(const long*)&sH[cur][aaddr[s][i]];
      #pragma unroll
      for (int j = 0; j < 4; ++j) bv[j] = *(const long*)&sW[cur][baddr[s][j]];
      #pragma unroll
      for (int i = 0; i < 4; ++i)
        #pragma unroll
        for (int j = 0; j < 4; ++j)
          acc[i][j] = __builtin_amdgcn_mfma_f32_16x16x32_fp8_fp8(av[i], bv[j], acc[i][j], 0, 0, 0);
    }
  }

  #pragma unroll
  for (int i = 0; i < 4; ++i)
    #pragma unroll
    for (int j = 0; j < 4; ++j)
      #pragma unroll
      for (int r = 0; r < 4; ++r) {
        int m = m0 + wm * 64 + i * 16 + quad * 4 + r;
        int n = n0 + wn * 64 + j * 16 + l15;
        size_t o = (size_t)m * 256 + n;
        O[o] = X[o] + acc[i][j][r] * (1.f / 256.f);
      }
}

extern "C" void kernel_launch(void* const* d_in, const int* in_sizes, int n_in,
                              void* d_out, int out_size, void* d_ws, size_t ws_size,
                              hipStream_t stream) {
  const float* x   = (const float*)d_in[0];
  const float* iw  = (const float*)d_in[1];
  const float* gg  = (const float*)d_in[2];
  const float* lnw = (const float*)d_in[3];
  const float* lnb = (const float*)d_in[4];
  const float* Wg  = (const float*)d_in[5];
  const float* Wu  = (const float*)d_in[6];
  const float* Wd  = (const float*)d_in[7];
  float* out = (float*)d_out;

  char* ws = (char*)d_ws;
  __bf16*        flat = (__bf16*)(ws);                       // 32 MB
  unsigned char* h    = (unsigned char*)(ws + 33554432);     // 64 MB
  __bf16*        Bg   = (__bf16*)(ws + 100663296);           // 512 KB
  __bf16*        Bu   = (__bf16*)(ws + 101187584);           // 512 KB
  unsigned char* Bd   = (unsigned char*)(ws + 101711872);    // 256 KB

  transpose_all<<<dim3(256, 3), 256, 0, stream>>>(Wg, Wu, Wd, Bg, Bu, Bd);
  geo_ln<<<2048, 256, 0, stream>>>(x, iw, gg, lnw, lnb, flat);
  gemm_gateup<<<dim3(16, 512), 256, 0, stream>>>(flat, Bg, Bu, h);
  gemm_down<<<dim3(2, 512), 256, 0, stream>>>(h, Bd, x, out);
}